// Round 2
// baseline (426.217 us; speedup 1.0000x reference)
//
#include <hip/hip_runtime.h>

#define HID 512
#define OUTD 7
#define EPSV 1e-5f
#define PR 32     // pool_reduce output rows

typedef __attribute__((ext_vector_type(8))) short bf16x8;
typedef __attribute__((ext_vector_type(4))) float f32x4;
typedef __attribute__((ext_vector_type(2))) float f32x2;
typedef unsigned short ushort_t;
typedef unsigned int uint_t;
typedef unsigned char uchar_t;

// ---------------- bf16 helpers ----------------
__device__ __forceinline__ ushort_t f2bf(float f) {
    uint_t u = __float_as_uint(f);
    u = (u + 0x7fffu + ((u >> 16) & 1u)) >> 16;    // RNE
    return (ushort_t)u;
}
__device__ __forceinline__ float bflo(uint_t u) { return __uint_as_float(u << 16); }
__device__ __forceinline__ float bfhi(uint_t u) { return __uint_as_float(u & 0xffff0000u); }

// ---------------- fp8 e4m3 (OCP) helpers — HW cvt ----------------
__device__ __forceinline__ void dec4(uint_t v, float* f) {
    f32x2 p0 = __builtin_amdgcn_cvt_pk_f32_fp8(v, false);
    f32x2 p1 = __builtin_amdgcn_cvt_pk_f32_fp8(v, true);
    f[0] = p0.x; f[1] = p0.y; f[2] = p1.x; f[3] = p1.y;
}
__device__ __forceinline__ uint_t enc4(float a, float b, float c, float d) {
    uint_t r = __builtin_amdgcn_cvt_pk_fp8_f32(a, b, 0, false);
    r = __builtin_amdgcn_cvt_pk_fp8_f32(c, d, r, true);
    return r;
}

// async global->LDS, 16B per lane; LDS dest is wave-uniform base + lane*16
__device__ __forceinline__ void gload_lds16(const ushort_t* g, ushort_t* l) {
    __builtin_amdgcn_global_load_lds(
        (const __attribute__((address_space(1))) uint_t*)g,
        (__attribute__((address_space(3))) uint_t*)l, 16, 0, 0);
}

// ---------------- setup: deg count + weight transpose (merged, independent) ----------------
__global__ __launch_bounds__(256) void deg_wtrans(
        const int* __restrict__ dst, int* __restrict__ deg, int E, int degB,
        const float* __restrict__ W0, const float* __restrict__ W1,
        const float* __restrict__ W2, const float* __restrict__ W3,
        ushort_t* __restrict__ T0, ushort_t* __restrict__ T1,
        ushort_t* __restrict__ T2, ushort_t* __restrict__ T3) {
    __shared__ ushort_t tile[32][33];
    if ((int)blockIdx.x < degB) {
        int e = blockIdx.x * 256 + threadIdx.x;
        if (e < E) atomicAdd(&deg[dst[e]], 1);
        return;
    }
    int id = blockIdx.x - degB;
    const float* W; ushort_t* T; int K;
    if (id < 64)       { W = W0; T = T0; K = 128; }
    else if (id < 320) { W = W1; T = T1; K = 512; id -= 64; }
    else if (id < 576) { W = W2; T = T2; K = 512; id -= 320; }
    else               { W = W3; T = T3; K = 512; id -= 576; }
    const int tn = id & 15;        // n-tile (512/32)
    const int tk = id >> 4;        // k-tile
    const int t = threadIdx.x;
    const int r = t >> 3;          // 0..31
    const int c4 = (t & 7) * 4;    // 0,4,..,28
    const float4 v = *(const float4*)&W[(size_t)(tk * 32 + r) * HID + tn * 32 + c4];
    tile[r][c4 + 0] = f2bf(v.x); tile[r][c4 + 1] = f2bf(v.y);
    tile[r][c4 + 2] = f2bf(v.z); tile[r][c4 + 3] = f2bf(v.w);
    __syncthreads();
    ushort4 ov = make_ushort4(tile[c4 + 0][r], tile[c4 + 1][r],
                              tile[c4 + 2][r], tile[c4 + 3][r]);
    *(ushort4*)&T[(size_t)(tn * 32 + r) * K + tk * 32 + c4] = ov;
}

// ---------------- hierarchical scan (2 phases) ----------------

__global__ void scan1(const int* __restrict__ deg, int* __restrict__ off,
                      int* __restrict__ partial, float* __restrict__ dinv, int N) {
    __shared__ int s[256];
    const int t = threadIdx.x;
    const int i = blockIdx.x * 256 + t;
    int d = (i < N) ? deg[i] : 0;
    if (i < N) dinv[i] = rsqrtf((float)(d + 1));   // +1 self loop
    s[t] = d;
    __syncthreads();
#pragma unroll
    for (int ofs = 1; ofs < 256; ofs <<= 1) {
        int v = (t >= ofs) ? s[t - ofs] : 0;
        __syncthreads();
        s[t] += v;
        __syncthreads();
    }
    if (i < N) off[i] = s[t] - d;
    if (t == 255) partial[blockIdx.x] = s[255];
}

__global__ void scan23(int* __restrict__ off, const int* __restrict__ partial,
                       int* __restrict__ cursor, int N, int E, int nb) {
    __shared__ int s[256];
    __shared__ int ex[256];
    const int t = threadIdx.x;
    int d = (t < nb) ? partial[t] : 0;
    s[t] = d;
    __syncthreads();
#pragma unroll
    for (int ofs = 1; ofs < 256; ofs <<= 1) {
        int v = (t >= ofs) ? s[t - ofs] : 0;
        __syncthreads();
        s[t] += v;
        __syncthreads();
    }
    ex[t] = s[t] - d;
    __syncthreads();
    int i = blockIdx.x * 256 + t;
    if (i < N) {
        int v = off[i] + ex[i >> 8];
        off[i] = v;
        cursor[i] = v;
    } else if (i == N) {
        off[N] = E;
    }
}

// ---------------- fused: CSR fill + x -> fp8*dinv ----------------

__global__ void fill_cvt(const int* __restrict__ src, const int* __restrict__ dst,
                         int* __restrict__ cursor, int* __restrict__ srcs, int E,
                         const float* __restrict__ x, const float* __restrict__ dinv,
                         ushort_t* __restrict__ xb, int pairs) {
    int i = blockIdx.x * blockDim.x + threadIdx.x;
    if (i < E) { int p = atomicAdd(&cursor[dst[i]], 1); srcs[p] = src[i]; return; }
    i -= E;
    if (i < pairs) {
        float dr = dinv[i >> 6];                      // row = 2i/128
        float a = x[2 * i] * dr, b = x[2 * i + 1] * dr;
        uint_t d = __builtin_amdgcn_cvt_pk_fp8_f32(a, b, 0, false);
        xb[i] = (ushort_t)(d & 0xffffu);
    }
}

// ---------------- aggregation: fp8 gather, multi-edge wave-instructions ----------------
// R14 structure — 4 gathers in flight (deeper ILP regressed, R15). Output bf16
// (GEMM A operand read exactly once; fp8 there only bought GEMM decode-VALU, R16).

__global__ __launch_bounds__(256) void csr_agg_512(
        const uchar_t* __restrict__ xs, const int* __restrict__ off,
        const int* __restrict__ srcs, const float* __restrict__ dinv,
        ushort_t* __restrict__ ax, int N) {
    int gtid = blockIdx.x * 256 + threadIdx.x;
    int r = gtid >> 6, lane = gtid & 63;
    if (r >= N) return;
    const int half = lane >> 5, l32 = lane & 31;
    const uint4* xb = (const uint4*)xs;    // row stride = 32 uint4 (512 B)
    float a[16];
    if (half == 0) {
        uint4 v = xb[(size_t)r * 32 + l32];
        dec4(v.x, a); dec4(v.y, a + 4); dec4(v.z, a + 8); dec4(v.w, a + 12);
    } else {
#pragma unroll
        for (int q = 0; q < 16; q++) a[q] = 0.f;
    }
    int e = off[r];
    const int e1 = off[r + 1];
    for (; e + 8 <= e1; e += 8) {
        int si[4]; uint4 vi[4];
#pragma unroll
        for (int j = 0; j < 4; j++) si[j] = srcs[e + 2 * j + half];
#pragma unroll
        for (int j = 0; j < 4; j++) vi[j] = xb[(size_t)si[j] * 32 + l32];
#pragma unroll
        for (int j = 0; j < 4; j++) {
            float f[16];
            dec4(vi[j].x, f); dec4(vi[j].y, f + 4); dec4(vi[j].z, f + 8); dec4(vi[j].w, f + 12);
#pragma unroll
            for (int q = 0; q < 16; q++) a[q] += f[q];
        }
    }
    for (; e < e1; e += 2) {
        int idx = e + half;
        bool valid = idx < e1;
        int s = srcs[valid ? idx : e];
        uint4 v = xb[(size_t)s * 32 + l32];
        if (!valid) { v.x = 0; v.y = 0; v.z = 0; v.w = 0; }
        float f[16];
        dec4(v.x, f); dec4(v.y, f + 4); dec4(v.z, f + 8); dec4(v.w, f + 12);
#pragma unroll
        for (int q = 0; q < 16; q++) a[q] += f[q];
    }
#pragma unroll
    for (int q = 0; q < 16; q++) a[q] += __shfl_xor(a[q], 32);
    {
        float dr = dinv[r];
        const int b = half * 8;
        uint_t w0 = (uint_t)f2bf(a[b + 0] * dr) | ((uint_t)f2bf(a[b + 1] * dr) << 16);
        uint_t w1 = (uint_t)f2bf(a[b + 2] * dr) | ((uint_t)f2bf(a[b + 3] * dr) << 16);
        uint_t w2 = (uint_t)f2bf(a[b + 4] * dr) | ((uint_t)f2bf(a[b + 5] * dr) << 16);
        uint_t w3 = (uint_t)f2bf(a[b + 6] * dr) | ((uint_t)f2bf(a[b + 7] * dr) << 16);
        ((uint4*)ax)[(size_t)r * 64 + l32 * 2 + half] = make_uint4(w0, w1, w2, w3);
    }
}

__global__ __launch_bounds__(256) void csr_agg_128(
        const uchar_t* __restrict__ xs, const int* __restrict__ off,
        const int* __restrict__ srcs, const float* __restrict__ dinv,
        ushort_t* __restrict__ ax, int N) {
    int gtid = blockIdx.x * 256 + threadIdx.x;
    int r = gtid >> 6, lane = gtid & 63;
    if (r >= N) return;
    const int sub = lane >> 3, l8 = lane & 7;   // 8 edge slots x 8 col-chunks (16B)
    const uint4* xb = (const uint4*)xs;         // row stride = 8 uint4 (128 B)
    float a[16];
    if (sub == 0) {
        uint4 v = xb[(size_t)r * 8 + l8];
        dec4(v.x, a); dec4(v.y, a + 4); dec4(v.z, a + 8); dec4(v.w, a + 12);
    } else {
#pragma unroll
        for (int q = 0; q < 16; q++) a[q] = 0.f;
    }
    const int e1 = off[r + 1];
    for (int e = off[r]; e < e1; e += 8) {
        int idx = e + sub;
        bool valid = idx < e1;
        int s = srcs[valid ? idx : e];
        uint4 v = xb[(size_t)s * 8 + l8];
        if (!valid) { v.x = 0; v.y = 0; v.z = 0; v.w = 0; }
        float f[16];
        dec4(v.x, f); dec4(v.y, f + 4); dec4(v.z, f + 8); dec4(v.w, f + 12);
#pragma unroll
        for (int q = 0; q < 16; q++) a[q] += f[q];
    }
#pragma unroll
    for (int q = 0; q < 16; q++) a[q] += __shfl_xor(a[q], 8);
#pragma unroll
    for (int q = 0; q < 16; q++) a[q] += __shfl_xor(a[q], 16);
#pragma unroll
    for (int q = 0; q < 16; q++) a[q] += __shfl_xor(a[q], 32);
    if (sub < 2) {
        float dr = dinv[r];
        const int b = sub * 8;
        uint_t w0 = (uint_t)f2bf(a[b + 0] * dr) | ((uint_t)f2bf(a[b + 1] * dr) << 16);
        uint_t w1 = (uint_t)f2bf(a[b + 2] * dr) | ((uint_t)f2bf(a[b + 3] * dr) << 16);
        uint_t w2 = (uint_t)f2bf(a[b + 4] * dr) | ((uint_t)f2bf(a[b + 5] * dr) << 16);
        uint_t w3 = (uint_t)f2bf(a[b + 6] * dr) | ((uint_t)f2bf(a[b + 7] * dr) << 16);
        ((uint4*)ax)[(size_t)r * 16 + l8 * 2 + sub] = make_uint4(w0, w1, w2, w3);
    }
}

// ---------------- fused MFMA GEMM + LayerNorm(+ReLU) epilogue ----------------
// R17: tile = 32 rows x FULL 512 cols so each row's LN stats live in one block.
// 4 waves, each 32x128 (2 m-frags x 8 n-frags of 16x16x32). OPERAND-SWAPPED
// mfma(bfr, af): D holds C^T fragments -> lane owns row m = im*16+l16 with
// 32 cols (8 jn x 4 rg, rg consecutive) -> row stats via 2 shfl_xor (quads)
// + 1KB LDS cross-wave reduce; fp8 out packs rg0..3 into one enc4 uint.
// POOL=1 (layer 3): per-block column sums -> pbuf row (replaces ln_pool).
// Eliminates ln_relu/ln_pool kernels and the hb 20MB round-trip entirely.
// B (Wt, <=512KB) is L2-resident per XCD; staged 64KB/K-step, swizzled chunks.

template<int POOL>
__global__ __launch_bounds__(256) void gemm_ln(
        const ushort_t* __restrict__ A, const ushort_t* __restrict__ Wt,
        const float* __restrict__ bias, const float* __restrict__ gamma,
        const float* __restrict__ beta, const float* __restrict__ dinv,
        uchar_t* __restrict__ out8, float* __restrict__ pbuf, int M, int K) {
    __shared__ __align__(16) ushort_t AsL[32 * 64];    // 4 KB
    __shared__ __align__(16) ushort_t BsL[512 * 64];   // 64 KB
    __shared__ float sred[4][32][2];
    const int t = threadIdx.x;
    const int wave = t >> 6, lane = t & 63;
    const int m0 = blockIdx.x * 32;
    const int wn = wave * 128;
    const int quad = lane >> 4, l16 = lane & 15;
    const int srow = lane >> 3;                // 0..7 within the 8-row stage group
    const int schunk = (lane & 7) ^ srow;      // pre-swizzled source 16B chunk
    const int sw = (l16 & 7) << 4;             // read-side XOR (bytes)

    f32x4 acc[2][8];
#pragma unroll
    for (int im = 0; im < 2; im++)
#pragma unroll
        for (int jn = 0; jn < 8; jn++) acc[im][jn] = (f32x4){0.f, 0.f, 0.f, 0.f};

    for (int k0 = 0; k0 < K; k0 += 64) {
        {   // A tile: 32 rows x 64k, one 1KB call per wave
            int gm = m0 + wave * 8 + srow;
            if (gm >= M) gm = M - 1;
            gload_lds16(A + (size_t)gm * K + k0 + (schunk << 3), AsL + wave * 512);
        }
#pragma unroll
        for (int j = 0; j < 16; j++) {   // B tile: 512 rows x 64k
            const int c = wave * 16 + j;
            gload_lds16(Wt + (size_t)(8 * c + srow) * K + k0 + (schunk << 3),
                        BsL + c * 512);
        }
        __syncthreads();
#pragma unroll
        for (int kk = 0; kk < 2; kk++) {
            const int kb = (kk * 4 + quad) << 4;
            bf16x8 af[2], bfr[8];
#pragma unroll
            for (int jn = 0; jn < 8; jn++)
                bfr[jn] = *(const bf16x8*)((const char*)BsL
                              + (wn + jn * 16 + l16) * 128 + (kb ^ sw));
#pragma unroll
            for (int im = 0; im < 2; im++)
                af[im] = *(const bf16x8*)((const char*)AsL
                              + (im * 16 + l16) * 128 + (kb ^ sw));
#pragma unroll
            for (int im = 0; im < 2; im++)
#pragma unroll
                for (int jn = 0; jn < 8; jn++)
                    acc[im][jn] = __builtin_amdgcn_mfma_f32_16x16x32_bf16(
                                      bfr[jn], af[im], acc[im][jn], 0, 0, 0);   // SWAPPED
        }
        __syncthreads();
    }

    // ---- epilogue: lane owns rows m = m0+im*16+l16, cols wn+jn*16+quad*4+rg ----
    float4 bias4[8];
#pragma unroll
    for (int jn = 0; jn < 8; jn++)
        bias4[jn] = *(const float4*)&bias[wn + jn * 16 + quad * 4];

#pragma unroll
    for (int im = 0; im < 2; im++) {
        float s = 0.f, q = 0.f;
#pragma unroll
        for (int jn = 0; jn < 8; jn++) {
#pragma unroll
            for (int rg = 0; rg < 4; rg++) {
                float h = acc[im][jn][rg] + ((const float*)&bias4[jn])[rg];
                s += h; q += h * h;
            }
        }
        s += __shfl_xor(s, 16); s += __shfl_xor(s, 32);
        q += __shfl_xor(q, 16); q += __shfl_xor(q, 32);
        if (quad == 0) { sred[wave][im * 16 + l16][0] = s; sred[wave][im * 16 + l16][1] = q; }
    }
    __syncthreads();

    float cacc[8][4];
    if (POOL) {
#pragma unroll
        for (int jn = 0; jn < 8; jn++)
#pragma unroll
            for (int rg = 0; rg < 4; rg++) cacc[jn][rg] = 0.f;
    }

#pragma unroll
    for (int im = 0; im < 2; im++) {
        const int row = im * 16 + l16;
        const float st = sred[0][row][0] + sred[1][row][0] + sred[2][row][0] + sred[3][row][0];
        const float qt = sred[0][row][1] + sred[1][row][1] + sred[2][row][1] + sred[3][row][1];
        const float mu = st * (1.0f / HID);
        const float var = qt * (1.0f / HID) - mu * mu;
        const float rs = rsqrtf(var + EPSV);
        const int gm = m0 + row;
        const bool ok = gm < M;
        float dr = 0.f;
        if (!POOL) dr = ok ? dinv[gm] : 0.f;
#pragma unroll
        for (int jn = 0; jn < 8; jn++) {
            const float4 g4 = *(const float4*)&gamma[wn + jn * 16 + quad * 4];
            const float4 b4 = *(const float4*)&beta[wn + jn * 16 + quad * 4];
            float o[4];
#pragma unroll
            for (int rg = 0; rg < 4; rg++) {
                float h = acc[im][jn][rg] + ((const float*)&bias4[jn])[rg];
                o[rg] = fmaxf((h - mu) * rs * ((const float*)&g4)[rg]
                              + ((const float*)&b4)[rg], 0.f);
            }
            if (POOL) {
#pragma unroll
                for (int rg = 0; rg < 4; rg++) cacc[jn][rg] += ok ? o[rg] : 0.f;
            } else if (ok) {
                *(uint_t*)(out8 + (size_t)gm * HID + wn + jn * 16 + quad * 4) =
                    enc4(o[0] * dr, o[1] * dr, o[2] * dr, o[3] * dr);
            }
        }
    }

    if (POOL) {
        // reduce column sums over the 16 l16-lanes (rows), then one writer/quad
#pragma unroll
        for (int jn = 0; jn < 8; jn++)
#pragma unroll
            for (int rg = 0; rg < 4; rg++) {
                float v = cacc[jn][rg];
                v += __shfl_xor(v, 1); v += __shfl_xor(v, 2);
                v += __shfl_xor(v, 4); v += __shfl_xor(v, 8);
                cacc[jn][rg] = v;
            }
        if (l16 == 0) {
#pragma unroll
            for (int jn = 0; jn < 8; jn++) {
                float4 v = make_float4(cacc[jn][0], cacc[jn][1], cacc[jn][2], cacc[jn][3]);
                *(float4*)&pbuf[(size_t)blockIdx.x * HID + wn + jn * 16 + quad * 4] = v;
            }
        }
    }
}

// ---------------- hierarchical pool partial reduction: NB rows -> PR rows ----------------

__global__ __launch_bounds__(256) void pool_reduce(
        const float* __restrict__ pbuf, float* __restrict__ pbuf2, int NB) {
    const int t = threadIdx.x;
    const int b = blockIdx.x;
    const int R = (NB + PR - 1) / PR;
    float2 s = make_float2(0.f, 0.f);
    for (int u = 0; u < R; u++) {
        int r = b * R + u;
        if (r < NB) {
            const float2 v = ((const float2*)(pbuf + (size_t)r * HID))[t];
            s.x += v.x; s.y += v.y;
        }
    }
    ((float2*)(pbuf2 + (size_t)b * HID))[t] = s;
}

// ---------------- output head: reduce PR partials + project to 7 outs ----------------

__global__ void out_kernel(const float* __restrict__ pbuf2, const float* __restrict__ Wout,
                           const float* __restrict__ bout, float* __restrict__ out, int N) {
    __shared__ float red[256];
    int t = threadIdx.x;
    float g0 = 0.f, g1 = 0.f;
#pragma unroll
    for (int p = 0; p < PR; p += 8) {
#pragma unroll
        for (int u = 0; u < 8; u++) {
            const float2 v = ((const float2*)(pbuf2 + (size_t)(p + u) * HID))[t];
            g0 += v.x; g1 += v.y;
        }
    }
    float invn = 1.0f / (float)N;
    for (int o = 0; o < OUTD; o++) {
        float pr = g0 * Wout[(2 * t) * OUTD + o] + g1 * Wout[(2 * t + 1) * OUTD + o];
        red[t] = pr;
        __syncthreads();
        for (int sft = 128; sft > 0; sft >>= 1) {
            if (t < sft) red[t] += red[t + sft];
            __syncthreads();
        }
        if (t == 0) out[o] = red[0] * invn + bout[o];
        __syncthreads();
    }
}

// ---------------- launch ----------------

extern "C" void kernel_launch(void* const* d_in, const int* in_sizes, int n_in,
                              void* d_out, int out_size, void* d_ws, size_t ws_size,
                              hipStream_t stream) {
    const float* x  = (const float*)d_in[0];
    const int*   ei = (const int*)d_in[1];
    const int N = in_sizes[0] / 128;
    const int E = in_sizes[1] / 2;
    const int* src = ei;
    const int* dst = ei + E;
    const float* Ws[4] = {(const float*)d_in[2], (const float*)d_in[4],
                          (const float*)d_in[6], (const float*)d_in[8]};
    const float* bs[4] = {(const float*)d_in[3], (const float*)d_in[5],
                          (const float*)d_in[7], (const float*)d_in[9]};
    const float* gamma = (const float*)d_in[10];
    const float* beta  = (const float*)d_in[11];
    const float* Wout  = (const float*)d_in[12];
    const float* bout  = (const float*)d_in[13];
    float* out = (float*)d_out;

    const int NBM = (N + 31) / 32;                   // gemm_ln blocks (pool partial rows)

    // workspace layout (16B-aligned chunks first)
    char* p = (char*)d_ws;
    ushort_t* axb = (ushort_t*)p;  p += sizeof(ushort_t) * (size_t)N * HID;   // agg out bf16 (gemm A)
    uchar_t*  ho8 = (uchar_t*)p;   p += (size_t)N * HID;                      // fp8 LN out (agg input)
    uchar_t*  xb8 = ho8;           // alias: fp8 x (N*128B, pre-scaled) until gemm_ln(l0) overwrites
    ushort_t* Wt[4];
    Wt[0] = (ushort_t*)p;          p += sizeof(ushort_t) * 128 * HID;
    Wt[1] = (ushort_t*)p;          p += sizeof(ushort_t) * HID * HID;
    Wt[2] = (ushort_t*)p;          p += sizeof(ushort_t) * HID * HID;
    Wt[3] = (ushort_t*)p;          p += sizeof(ushort_t) * HID * HID;
    float* dinv  = (float*)p;      p += sizeof(float) * N;
    float* pbuf  = (float*)p;      p += sizeof(float) * (size_t)(NBM + 4) * HID; // pool partials
    float* pbuf2 = (float*)p;      p += sizeof(float) * PR * HID;             // 64 KB stage-2
    int* deg    = (int*)p;         p += sizeof(int) * N;
    int* off    = (int*)p;         p += sizeof(int) * (N + 4);
    int* cursor = (int*)p;         p += sizeof(int) * N;
    int* partial= (int*)p;         p += sizeof(int) * 256;
    int* srcs   = (int*)p;         // E ints

    const int nb = (N + 255) / 256;
    const int degB = (E + 255) / 256;

    // ---- setup: CSR build + conversions (once) ----
    hipMemsetAsync(deg, 0, sizeof(int) * N, stream);   // memset node: graph-capturable
    deg_wtrans<<<degB + 832, 256, 0, stream>>>(dst, deg, E, degB,
                                               Ws[0], Ws[1], Ws[2], Ws[3],
                                               Wt[0], Wt[1], Wt[2], Wt[3]);
    scan1<<<nb, 256, 0, stream>>>(deg, off, partial, dinv, N);
    scan23<<<(N + 256) / 256, 256, 0, stream>>>(off, partial, cursor, N, E, nb);
    {
        int pairs = N * 64;   // N*128/2
        int tot = E + pairs;
        fill_cvt<<<(tot + 255) / 256, 256, 0, stream>>>(src, dst, cursor, srcs, E,
                                                        x, dinv, (ushort_t*)xb8, pairs);
    }

    for (int l = 0; l < 4; l++) {
        const int K = (l == 0) ? 128 : HID;
        if (l == 0)
            csr_agg_128<<<(N * 64 + 255) / 256, 256, 0, stream>>>(xb8, off, srcs, dinv, axb, N);
        else
            csr_agg_512<<<(N * 64 + 255) / 256, 256, 0, stream>>>(ho8, off, srcs, dinv, axb, N);
        if (l < 3)
            gemm_ln<0><<<NBM, 256, 0, stream>>>(axb, Wt[l], bs[l], gamma, beta, dinv,
                                                ho8, pbuf, N, K);
        else
            gemm_ln<1><<<NBM, 256, 0, stream>>>(axb, Wt[l], bs[l], gamma, beta, dinv,
                                                ho8, pbuf, N, K);
    }
    pool_reduce<<<PR, 256, 0, stream>>>(pbuf, pbuf2, NBM);
    out_kernel<<<1, 256, 0, stream>>>(pbuf2, Wout, bout, out, N);
}

// Round 3
// 375.968 us; speedup vs baseline: 1.1337x; 1.1337x over previous
//
#include <hip/hip_runtime.h>

#define HID 512
#define OUTD 7
#define EPSV 1e-5f
#define PR 32     // pool_reduce output rows

typedef __attribute__((ext_vector_type(8))) short bf16x8;
typedef __attribute__((ext_vector_type(4))) float f32x4;
typedef __attribute__((ext_vector_type(2))) float f32x2;
typedef unsigned short ushort_t;
typedef unsigned int uint_t;
typedef unsigned char uchar_t;

// ---------------- bf16 helpers ----------------
__device__ __forceinline__ ushort_t f2bf(float f) {
    uint_t u = __float_as_uint(f);
    u = (u + 0x7fffu + ((u >> 16) & 1u)) >> 16;    // RNE
    return (ushort_t)u;
}
__device__ __forceinline__ float bflo(uint_t u) { return __uint_as_float(u << 16); }
__device__ __forceinline__ float bfhi(uint_t u) { return __uint_as_float(u & 0xffff0000u); }

// ---------------- fp8 e4m3 (OCP) helpers — HW cvt ----------------
__device__ __forceinline__ void dec4(uint_t v, float* f) {
    f32x2 p0 = __builtin_amdgcn_cvt_pk_f32_fp8(v, false);
    f32x2 p1 = __builtin_amdgcn_cvt_pk_f32_fp8(v, true);
    f[0] = p0.x; f[1] = p0.y; f[2] = p1.x; f[3] = p1.y;
}
__device__ __forceinline__ uint_t enc4(float a, float b, float c, float d) {
    uint_t r = __builtin_amdgcn_cvt_pk_fp8_f32(a, b, 0, false);
    r = __builtin_amdgcn_cvt_pk_fp8_f32(c, d, r, true);
    return r;
}

// async global->LDS, 16B per lane; LDS dest is wave-uniform base + lane*16
__device__ __forceinline__ void gload_lds16(const ushort_t* g, ushort_t* l) {
    __builtin_amdgcn_global_load_lds(
        (const __attribute__((address_space(1))) uint_t*)g,
        (__attribute__((address_space(3))) uint_t*)l, 16, 0, 0);
}

// ---------------- setup: deg count + weight transpose (merged, independent) ------
// R18: Wt is emitted in MFMA-FRAGMENT layout Wf[n16][kc][l16][8 bf16]
// (n16 = n>>4, l16 = n&15, kc = k>>3) so the GEMM's B-fragment load is one
// fully-coalesced 1KB global load per wave: addr = base + lane*16B.
__global__ __launch_bounds__(256) void deg_wtrans(
        const int* __restrict__ dst, int* __restrict__ deg, int E, int degB,
        const float* __restrict__ W0, const float* __restrict__ W1,
        const float* __restrict__ W2, const float* __restrict__ W3,
        ushort_t* __restrict__ T0, ushort_t* __restrict__ T1,
        ushort_t* __restrict__ T2, ushort_t* __restrict__ T3) {
    __shared__ ushort_t tile[32][33];
    if ((int)blockIdx.x < degB) {
        int e = blockIdx.x * 256 + threadIdx.x;
        if (e < E) atomicAdd(&deg[dst[e]], 1);
        return;
    }
    int id = blockIdx.x - degB;
    const float* W; ushort_t* T; int K;
    if (id < 64)       { W = W0; T = T0; K = 128; }
    else if (id < 320) { W = W1; T = T1; K = 512; id -= 64; }
    else if (id < 576) { W = W2; T = T2; K = 512; id -= 320; }
    else               { W = W3; T = T3; K = 512; id -= 576; }
    const int tn = id & 15;        // n-tile (512/32)
    const int tk = id >> 4;        // k-tile
    const int t = threadIdx.x;
    const int r = t >> 3;          // 0..31
    const int c4 = (t & 7) * 4;    // 0,4,..,28
    const float4 v = *(const float4*)&W[(size_t)(tk * 32 + r) * HID + tn * 32 + c4];
    tile[r][c4 + 0] = f2bf(v.x); tile[r][c4 + 1] = f2bf(v.y);
    tile[r][c4 + 2] = f2bf(v.z); tile[r][c4 + 3] = f2bf(v.w);
    __syncthreads();
    ushort4 ov = make_ushort4(tile[c4 + 0][r], tile[c4 + 1][r],
                              tile[c4 + 2][r], tile[c4 + 3][r]);
    // fragment-layout address
    const int n   = tn * 32 + r;          // output row (col of W)
    const int n16 = n >> 4, l16n = n & 15;
    const int kb  = tk * 32 + c4;         // k of first element
    const int kc  = kb >> 3, k8 = kb & 7; // k8 in {0,4}
    size_t idx = ((((size_t)n16 * (K >> 3) + kc) << 4) + l16n) * 8 + k8;
    *(ushort4*)&T[idx] = ov;
}

// ---------------- hierarchical scan (2 phases) ----------------

__global__ void scan1(const int* __restrict__ deg, int* __restrict__ off,
                      int* __restrict__ partial, float* __restrict__ dinv, int N) {
    __shared__ int s[256];
    const int t = threadIdx.x;
    const int i = blockIdx.x * 256 + t;
    int d = (i < N) ? deg[i] : 0;
    if (i < N) dinv[i] = rsqrtf((float)(d + 1));   // +1 self loop
    s[t] = d;
    __syncthreads();
#pragma unroll
    for (int ofs = 1; ofs < 256; ofs <<= 1) {
        int v = (t >= ofs) ? s[t - ofs] : 0;
        __syncthreads();
        s[t] += v;
        __syncthreads();
    }
    if (i < N) off[i] = s[t] - d;
    if (t == 255) partial[blockIdx.x] = s[255];
}

__global__ void scan23(int* __restrict__ off, const int* __restrict__ partial,
                       int* __restrict__ cursor, int N, int E, int nb) {
    __shared__ int s[256];
    __shared__ int ex[256];
    const int t = threadIdx.x;
    int d = (t < nb) ? partial[t] : 0;
    s[t] = d;
    __syncthreads();
#pragma unroll
    for (int ofs = 1; ofs < 256; ofs <<= 1) {
        int v = (t >= ofs) ? s[t - ofs] : 0;
        __syncthreads();
        s[t] += v;
        __syncthreads();
    }
    ex[t] = s[t] - d;
    __syncthreads();
    int i = blockIdx.x * 256 + t;
    if (i < N) {
        int v = off[i] + ex[i >> 8];
        off[i] = v;
        cursor[i] = v;
    } else if (i == N) {
        off[N] = E;
    }
}

// ---------------- fused: CSR fill + x -> fp8*dinv ----------------

__global__ void fill_cvt(const int* __restrict__ src, const int* __restrict__ dst,
                         int* __restrict__ cursor, int* __restrict__ srcs, int E,
                         const float* __restrict__ x, const float* __restrict__ dinv,
                         ushort_t* __restrict__ xb, int pairs) {
    int i = blockIdx.x * blockDim.x + threadIdx.x;
    if (i < E) { int p = atomicAdd(&cursor[dst[i]], 1); srcs[p] = src[i]; return; }
    i -= E;
    if (i < pairs) {
        float dr = dinv[i >> 6];                      // row = 2i/128
        float a = x[2 * i] * dr, b = x[2 * i + 1] * dr;
        uint_t d = __builtin_amdgcn_cvt_pk_fp8_f32(a, b, 0, false);
        xb[i] = (ushort_t)(d & 0xffffu);
    }
}

// ---------------- aggregation: fp8 gather, multi-edge wave-instructions ----------------
// R14 structure — 4 gathers in flight (deeper ILP regressed, R15). Output bf16
// (GEMM A operand read exactly once; fp8 there only bought GEMM decode-VALU, R16).

__global__ __launch_bounds__(256) void csr_agg_512(
        const uchar_t* __restrict__ xs, const int* __restrict__ off,
        const int* __restrict__ srcs, const float* __restrict__ dinv,
        ushort_t* __restrict__ ax, int N) {
    int gtid = blockIdx.x * 256 + threadIdx.x;
    int r = gtid >> 6, lane = gtid & 63;
    if (r >= N) return;
    const int half = lane >> 5, l32 = lane & 31;
    const uint4* xb = (const uint4*)xs;    // row stride = 32 uint4 (512 B)
    float a[16];
    if (half == 0) {
        uint4 v = xb[(size_t)r * 32 + l32];
        dec4(v.x, a); dec4(v.y, a + 4); dec4(v.z, a + 8); dec4(v.w, a + 12);
    } else {
#pragma unroll
        for (int q = 0; q < 16; q++) a[q] = 0.f;
    }
    int e = off[r];
    const int e1 = off[r + 1];
    for (; e + 8 <= e1; e += 8) {
        int si[4]; uint4 vi[4];
#pragma unroll
        for (int j = 0; j < 4; j++) si[j] = srcs[e + 2 * j + half];
#pragma unroll
        for (int j = 0; j < 4; j++) vi[j] = xb[(size_t)si[j] * 32 + l32];
#pragma unroll
        for (int j = 0; j < 4; j++) {
            float f[16];
            dec4(vi[j].x, f); dec4(vi[j].y, f + 4); dec4(vi[j].z, f + 8); dec4(vi[j].w, f + 12);
#pragma unroll
            for (int q = 0; q < 16; q++) a[q] += f[q];
        }
    }
    for (; e < e1; e += 2) {
        int idx = e + half;
        bool valid = idx < e1;
        int s = srcs[valid ? idx : e];
        uint4 v = xb[(size_t)s * 32 + l32];
        if (!valid) { v.x = 0; v.y = 0; v.z = 0; v.w = 0; }
        float f[16];
        dec4(v.x, f); dec4(v.y, f + 4); dec4(v.z, f + 8); dec4(v.w, f + 12);
#pragma unroll
        for (int q = 0; q < 16; q++) a[q] += f[q];
    }
#pragma unroll
    for (int q = 0; q < 16; q++) a[q] += __shfl_xor(a[q], 32);
    {
        float dr = dinv[r];
        const int b = half * 8;
        uint_t w0 = (uint_t)f2bf(a[b + 0] * dr) | ((uint_t)f2bf(a[b + 1] * dr) << 16);
        uint_t w1 = (uint_t)f2bf(a[b + 2] * dr) | ((uint_t)f2bf(a[b + 3] * dr) << 16);
        uint_t w2 = (uint_t)f2bf(a[b + 4] * dr) | ((uint_t)f2bf(a[b + 5] * dr) << 16);
        uint_t w3 = (uint_t)f2bf(a[b + 6] * dr) | ((uint_t)f2bf(a[b + 7] * dr) << 16);
        ((uint4*)ax)[(size_t)r * 64 + l32 * 2 + half] = make_uint4(w0, w1, w2, w3);
    }
}

__global__ __launch_bounds__(256) void csr_agg_128(
        const uchar_t* __restrict__ xs, const int* __restrict__ off,
        const int* __restrict__ srcs, const float* __restrict__ dinv,
        ushort_t* __restrict__ ax, int N) {
    int gtid = blockIdx.x * 256 + threadIdx.x;
    int r = gtid >> 6, lane = gtid & 63;
    if (r >= N) return;
    const int sub = lane >> 3, l8 = lane & 7;   // 8 edge slots x 8 col-chunks (16B)
    const uint4* xb = (const uint4*)xs;         // row stride = 8 uint4 (128 B)
    float a[16];
    if (sub == 0) {
        uint4 v = xb[(size_t)r * 8 + l8];
        dec4(v.x, a); dec4(v.y, a + 4); dec4(v.z, a + 8); dec4(v.w, a + 12);
    } else {
#pragma unroll
        for (int q = 0; q < 16; q++) a[q] = 0.f;
    }
    const int e1 = off[r + 1];
    for (int e = off[r]; e < e1; e += 8) {
        int idx = e + sub;
        bool valid = idx < e1;
        int s = srcs[valid ? idx : e];
        uint4 v = xb[(size_t)s * 8 + l8];
        if (!valid) { v.x = 0; v.y = 0; v.z = 0; v.w = 0; }
        float f[16];
        dec4(v.x, f); dec4(v.y, f + 4); dec4(v.z, f + 8); dec4(v.w, f + 12);
#pragma unroll
        for (int q = 0; q < 16; q++) a[q] += f[q];
    }
#pragma unroll
    for (int q = 0; q < 16; q++) a[q] += __shfl_xor(a[q], 8);
#pragma unroll
    for (int q = 0; q < 16; q++) a[q] += __shfl_xor(a[q], 16);
#pragma unroll
    for (int q = 0; q < 16; q++) a[q] += __shfl_xor(a[q], 32);
    if (sub < 2) {
        float dr = dinv[r];
        const int b = sub * 8;
        uint_t w0 = (uint_t)f2bf(a[b + 0] * dr) | ((uint_t)f2bf(a[b + 1] * dr) << 16);
        uint_t w1 = (uint_t)f2bf(a[b + 2] * dr) | ((uint_t)f2bf(a[b + 3] * dr) << 16);
        uint_t w2 = (uint_t)f2bf(a[b + 4] * dr) | ((uint_t)f2bf(a[b + 5] * dr) << 16);
        uint_t w3 = (uint_t)f2bf(a[b + 6] * dr) | ((uint_t)f2bf(a[b + 7] * dr) << 16);
        ((uint4*)ax)[(size_t)r * 16 + l8 * 2 + sub] = make_uint4(w0, w1, w2, w3);
    }
}

// ---------------- fused MFMA GEMM + LayerNorm(+ReLU) epilogue ----------------
// R18: 64 rows x FULL 512 cols, 8 waves (512 thr). Wave owns a 64-col slice:
// acc[4 im][4 jn] of 16x16x32, OPERAND-SWAPPED mfma(bfr, af) -> lane owns row
// m = im*16+l16, cols wn+jn*16+quad*4+rg. B is NOT staged: read straight from
// L2-resident Wf in fragment layout (1KB coalesced load per fragment, register
// operands the compiler pipelines across barriers). Only A (8KB/step) goes
// through LDS. R17's 64KB-B-tile-per-step staging was the 52us bottleneck
// (MfmaUtil 7%, occupancy 8%, AI=31 FLOP/LDS-byte).

template<int POOL>
__global__ __launch_bounds__(512) void gemm_ln(
        const ushort_t* __restrict__ A, const ushort_t* __restrict__ Wf,
        const float* __restrict__ bias, const float* __restrict__ gamma,
        const float* __restrict__ beta, const float* __restrict__ dinv,
        uchar_t* __restrict__ out8, float* __restrict__ pbuf, int M, int K) {
    __shared__ __align__(16) ushort_t AsL[64 * 64];    // 8 KB
    __shared__ float sred[8][64][2];                   // 4 KB
    const int t = threadIdx.x;
    const int wave = t >> 6, lane = t & 63;
    const int m0 = blockIdx.x * 64;
    const int wn = wave * 64;
    const int quad = lane >> 4, l16 = lane & 15;
    const int srow = lane >> 3;                // 0..7 within the 8-row stage group
    const int schunk = (lane & 7) ^ srow;      // pre-swizzled source 16B chunk
    const int sw = (l16 & 7) << 4;             // read-side XOR (bytes)
    const int K8 = K >> 3;

    f32x4 acc[4][4];
#pragma unroll
    for (int im = 0; im < 4; im++)
#pragma unroll
        for (int jn = 0; jn < 4; jn++) acc[im][jn] = (f32x4){0.f, 0.f, 0.f, 0.f};

    for (int k0 = 0; k0 < K; k0 += 64) {
        {   // A tile: 64 rows x 64k = 8KB; one 1KB call per wave (8 rows each)
            int gm = m0 + wave * 8 + srow;
            if (gm >= M) gm = M - 1;
            gload_lds16(A + (size_t)gm * K + k0 + (schunk << 3), AsL + wave * 512);
        }
        __syncthreads();
#pragma unroll
        for (int kk = 0; kk < 2; kk++) {
            const int kc = (k0 >> 3) + kk * 4 + quad;   // 16B k-chunk index
            bf16x8 bfr[4], af[4];
#pragma unroll
            for (int jn = 0; jn < 4; jn++)
                bfr[jn] = *(const bf16x8*)
                    &Wf[((((size_t)(wave * 4 + jn) * K8 + kc) << 4) + l16) * 8];
            const int kb = (kk * 4 + quad) << 4;
#pragma unroll
            for (int im = 0; im < 4; im++)
                af[im] = *(const bf16x8*)((const char*)AsL
                              + (im * 16 + l16) * 128 + (kb ^ sw));
#pragma unroll
            for (int im = 0; im < 4; im++)
#pragma unroll
                for (int jn = 0; jn < 4; jn++)
                    acc[im][jn] = __builtin_amdgcn_mfma_f32_16x16x32_bf16(
                                      bfr[jn], af[im], acc[im][jn], 0, 0, 0);   // SWAPPED
        }
        __syncthreads();
    }

    // ---- epilogue: lane owns rows m = m0+im*16+l16, cols wn+jn*16+quad*4+rg ----
    float4 bias4[4];
#pragma unroll
    for (int jn = 0; jn < 4; jn++)
        bias4[jn] = *(const float4*)&bias[wn + jn * 16 + quad * 4];

#pragma unroll
    for (int im = 0; im < 4; im++) {
        float s = 0.f, q = 0.f;
#pragma unroll
        for (int jn = 0; jn < 4; jn++) {
#pragma unroll
            for (int rg = 0; rg < 4; rg++) {
                float h = acc[im][jn][rg] + ((const float*)&bias4[jn])[rg];
                s += h; q += h * h;
            }
        }
        s += __shfl_xor(s, 16); s += __shfl_xor(s, 32);
        q += __shfl_xor(q, 16); q += __shfl_xor(q, 32);
        if (quad == 0) { sred[wave][im * 16 + l16][0] = s; sred[wave][im * 16 + l16][1] = q; }
    }
    __syncthreads();

    float cacc[4][4];
    if (POOL) {
#pragma unroll
        for (int jn = 0; jn < 4; jn++)
#pragma unroll
            for (int rg = 0; rg < 4; rg++) cacc[jn][rg] = 0.f;
    }

#pragma unroll
    for (int im = 0; im < 4; im++) {
        const int row = im * 16 + l16;
        float st = 0.f, qt = 0.f;
#pragma unroll
        for (int w = 0; w < 8; w++) { st += sred[w][row][0]; qt += sred[w][row][1]; }
        const float mu = st * (1.0f / HID);
        const float var = qt * (1.0f / HID) - mu * mu;
        const float rs = rsqrtf(var + EPSV);
        const int gm = m0 + row;
        const bool ok = gm < M;
        float dr = 0.f;
        if (!POOL) dr = ok ? dinv[gm] : 0.f;
#pragma unroll
        for (int jn = 0; jn < 4; jn++) {
            const float4 g4 = *(const float4*)&gamma[wn + jn * 16 + quad * 4];
            const float4 b4 = *(const float4*)&beta[wn + jn * 16 + quad * 4];
            float o[4];
#pragma unroll
            for (int rg = 0; rg < 4; rg++) {
                float h = acc[im][jn][rg] + ((const float*)&bias4[jn])[rg];
                o[rg] = fmaxf((h - mu) * rs * ((const float*)&g4)[rg]
                              + ((const float*)&b4)[rg], 0.f);
            }
            if (POOL) {
#pragma unroll
                for (int rg = 0; rg < 4; rg++) cacc[jn][rg] += ok ? o[rg] : 0.f;
            } else if (ok) {
                *(uint_t*)(out8 + (size_t)gm * HID + wn + jn * 16 + quad * 4) =
                    enc4(o[0] * dr, o[1] * dr, o[2] * dr, o[3] * dr);
            }
        }
    }

    if (POOL) {
        // reduce column sums over the 16 l16-lanes (rows), then one writer/quad
#pragma unroll
        for (int jn = 0; jn < 4; jn++)
#pragma unroll
            for (int rg = 0; rg < 4; rg++) {
                float v = cacc[jn][rg];
                v += __shfl_xor(v, 1); v += __shfl_xor(v, 2);
                v += __shfl_xor(v, 4); v += __shfl_xor(v, 8);
                cacc[jn][rg] = v;
            }
        if (l16 == 0) {
#pragma unroll
            for (int jn = 0; jn < 4; jn++) {
                float4 v = make_float4(cacc[jn][0], cacc[jn][1], cacc[jn][2], cacc[jn][3]);
                *(float4*)&pbuf[(size_t)blockIdx.x * HID + wn + jn * 16 + quad * 4] = v;
            }
        }
    }
}

// ---------------- hierarchical pool partial reduction: NB rows -> PR rows ----------------

__global__ __launch_bounds__(256) void pool_reduce(
        const float* __restrict__ pbuf, float* __restrict__ pbuf2, int NB) {
    const int t = threadIdx.x;
    const int b = blockIdx.x;
    const int R = (NB + PR - 1) / PR;
    float2 s = make_float2(0.f, 0.f);
    for (int u = 0; u < R; u++) {
        int r = b * R + u;
        if (r < NB) {
            const float2 v = ((const float2*)(pbuf + (size_t)r * HID))[t];
            s.x += v.x; s.y += v.y;
        }
    }
    ((float2*)(pbuf2 + (size_t)b * HID))[t] = s;
}

// ---------------- output head: reduce PR partials + project to 7 outs ----------------

__global__ void out_kernel(const float* __restrict__ pbuf2, const float* __restrict__ Wout,
                           const float* __restrict__ bout, float* __restrict__ out, int N) {
    __shared__ float red[256];
    int t = threadIdx.x;
    float g0 = 0.f, g1 = 0.f;
#pragma unroll
    for (int p = 0; p < PR; p += 8) {
#pragma unroll
        for (int u = 0; u < 8; u++) {
            const float2 v = ((const float2*)(pbuf2 + (size_t)(p + u) * HID))[t];
            g0 += v.x; g1 += v.y;
        }
    }
    float invn = 1.0f / (float)N;
    for (int o = 0; o < OUTD; o++) {
        float pr = g0 * Wout[(2 * t) * OUTD + o] + g1 * Wout[(2 * t + 1) * OUTD + o];
        red[t] = pr;
        __syncthreads();
        for (int sft = 128; sft > 0; sft >>= 1) {
            if (t < sft) red[t] += red[t + sft];
            __syncthreads();
        }
        if (t == 0) out[o] = red[0] * invn + bout[o];
        __syncthreads();
    }
}

// ---------------- launch ----------------

extern "C" void kernel_launch(void* const* d_in, const int* in_sizes, int n_in,
                              void* d_out, int out_size, void* d_ws, size_t ws_size,
                              hipStream_t stream) {
    const float* x  = (const float*)d_in[0];
    const int*   ei = (const int*)d_in[1];
    const int N = in_sizes[0] / 128;
    const int E = in_sizes[1] / 2;
    const int* src = ei;
    const int* dst = ei + E;
    const float* Ws[4] = {(const float*)d_in[2], (const float*)d_in[4],
                          (const float*)d_in[6], (const float*)d_in[8]};
    const float* bs[4] = {(const float*)d_in[3], (const float*)d_in[5],
                          (const float*)d_in[7], (const float*)d_in[9]};
    const float* gamma = (const float*)d_in[10];
    const float* beta  = (const float*)d_in[11];
    const float* Wout  = (const float*)d_in[12];
    const float* bout  = (const float*)d_in[13];
    float* out = (float*)d_out;

    const int NBM = (N + 63) / 64;                   // gemm_ln blocks (pool partial rows)

    // workspace layout (16B-aligned chunks first)
    char* p = (char*)d_ws;
    ushort_t* axb = (ushort_t*)p;  p += sizeof(ushort_t) * (size_t)N * HID;   // agg out bf16 (gemm A)
    uchar_t*  ho8 = (uchar_t*)p;   p += (size_t)N * HID;                      // fp8 LN out (agg input)
    uchar_t*  xb8 = ho8;           // alias: fp8 x (N*128B, pre-scaled) until gemm_ln(l0) overwrites
    ushort_t* Wt[4];
    Wt[0] = (ushort_t*)p;          p += sizeof(ushort_t) * 128 * HID;
    Wt[1] = (ushort_t*)p;          p += sizeof(ushort_t) * HID * HID;
    Wt[2] = (ushort_t*)p;          p += sizeof(ushort_t) * HID * HID;
    Wt[3] = (ushort_t*)p;          p += sizeof(ushort_t) * HID * HID;
    float* dinv  = (float*)p;      p += sizeof(float) * N;
    float* pbuf  = (float*)p;      p += sizeof(float) * (size_t)(NBM + 4) * HID; // pool partials
    float* pbuf2 = (float*)p;      p += sizeof(float) * PR * HID;             // 64 KB stage-2
    int* deg    = (int*)p;         p += sizeof(int) * N;
    int* off    = (int*)p;         p += sizeof(int) * (N + 4);
    int* cursor = (int*)p;         p += sizeof(int) * N;
    int* partial= (int*)p;         p += sizeof(int) * 256;
    int* srcs   = (int*)p;         // E ints

    const int nb = (N + 255) / 256;
    const int degB = (E + 255) / 256;

    // ---- setup: CSR build + conversions (once) ----
    hipMemsetAsync(deg, 0, sizeof(int) * N, stream);   // memset node: graph-capturable
    deg_wtrans<<<degB + 832, 256, 0, stream>>>(dst, deg, E, degB,
                                               Ws[0], Ws[1], Ws[2], Ws[3],
                                               Wt[0], Wt[1], Wt[2], Wt[3]);
    scan1<<<nb, 256, 0, stream>>>(deg, off, partial, dinv, N);
    scan23<<<(N + 256) / 256, 256, 0, stream>>>(off, partial, cursor, N, E, nb);
    {
        int pairs = N * 64;   // N*128/2
        int tot = E + pairs;
        fill_cvt<<<(tot + 255) / 256, 256, 0, stream>>>(src, dst, cursor, srcs, E,
                                                        x, dinv, (ushort_t*)xb8, pairs);
    }

    for (int l = 0; l < 4; l++) {
        const int K = (l == 0) ? 128 : HID;
        if (l == 0)
            csr_agg_128<<<(N * 64 + 255) / 256, 256, 0, stream>>>(xb8, off, srcs, dinv, axb, N);
        else
            csr_agg_512<<<(N * 64 + 255) / 256, 256, 0, stream>>>(ho8, off, srcs, dinv, axb, N);
        if (l < 3)
            gemm_ln<0><<<NBM, 512, 0, stream>>>(axb, Wt[l], bs[l], gamma, beta, dinv,
                                                ho8, pbuf, N, K);
        else
            gemm_ln<1><<<NBM, 512, 0, stream>>>(axb, Wt[l], bs[l], gamma, beta, dinv,
                                                ho8, pbuf, N, K);
    }
    pool_reduce<<<PR, 256, 0, stream>>>(pbuf, pbuf2, NBM);
    out_kernel<<<1, 256, 0, stream>>>(pbuf2, Wout, bout, out, N);
}